// Round 3
// baseline (533.887 us; speedup 1.0000x reference)
//
#include <hip/hip_runtime.h>
#include <math.h>

// ============================ CSR build ============================

__global__ void count_kernel(const int* __restrict__ dst, int* __restrict__ deg, int E) {
  int i = blockIdx.x * 256 + threadIdx.x;
  if (i < E) atomicAdd(&deg[dst[i]], 1);
}

// exclusive scan of (deg[i]+1) (+1 = self loop); single block, 8 vals/thread
__global__ void scan_kernel(const int* __restrict__ deg, int* __restrict__ rowptr, int n) {
  __shared__ int buf[1024];
  __shared__ int carry;
  if (threadIdx.x == 0) carry = 0;
  __syncthreads();
  for (int base = 0; base < n; base += 8192) {
    int v[8];
    int tsum = 0;
    int i0 = base + (int)threadIdx.x * 8;
#pragma unroll
    for (int k = 0; k < 8; ++k) {
      int i = i0 + k;
      v[k] = (i < n) ? (deg[i] + 1) : 0;
      tsum += v[k];
    }
    int incl = tsum;
    buf[threadIdx.x] = incl;
    __syncthreads();
    for (int s = 1; s < 1024; s <<= 1) {
      int t = (threadIdx.x >= (unsigned)s) ? buf[threadIdx.x - s] : 0;
      __syncthreads();
      incl += t;
      buf[threadIdx.x] = incl;
      __syncthreads();
    }
    int excl = carry + incl - tsum;
#pragma unroll
    for (int k = 0; k < 8; ++k) {
      int i = i0 + k;
      if (i < n) rowptr[i] = excl;
      excl += v[k];
    }
    int total = buf[1023];
    __syncthreads();
    if (threadIdx.x == 0) carry += total;
    __syncthreads();
  }
  if (threadIdx.x == 0) rowptr[n] = carry;
}

__global__ void scatter_kernel(const int* __restrict__ src, const int* __restrict__ dst,
                               const int* __restrict__ rowptr, int* __restrict__ wp,
                               int* __restrict__ col, int E, int n) {
  int i = blockIdx.x * 256 + threadIdx.x;
  if (i < E) {
    int d = dst[i];
    int p = rowptr[d] + atomicAdd(&wp[d], 1);
    col[p] = src[i];
  } else if (i < E + n) {
    int d = i - E;
    int p = rowptr[d] + atomicAdd(&wp[d], 1);
    col[p] = d;
  }
}

// ============================ fp32 GEMM ============================
// C[M,*] = A[M,K] @ B[K,*] (+bias). blockIdx.z adds aZ/bZ/cZ/biasZ element
// offsets (per-head batched projections). BN=64, BK=16, 256 threads,
// per-thread (BMt/16)x4 accumulator.

template <int BMt>
__global__ __launch_bounds__(256) void gemm_kernel(
    const float* __restrict__ A, const float* __restrict__ B,
    float* __restrict__ C, const float* __restrict__ bias,
    int M, int K, int lda, int ldb, int ldc,
    int aZ, int bZ, int cZ, int biasZ) {
  constexpr int BNt = 64, BKt = 16;
  constexpr int TM = BMt / 16;  // rows per thread (8 or 4)
  __shared__ float As[BKt][BMt + 4];
  __shared__ float Bs[BKt][BNt];
  const int z = blockIdx.z;
  A += (size_t)z * aZ;
  B += (size_t)z * bZ;
  C += (size_t)z * cZ;
  const int tid = threadIdx.x;
  const int bm = blockIdx.y * BMt;
  const int bn = blockIdx.x * BNt;
  const int tm = (tid >> 4) * TM;
  const int tn = (tid & 15) * 4;
  float acc[TM][4] = {};
  for (int k0 = 0; k0 < K; k0 += BKt) {
    // stage A: BMt x 16, float4 per thread-slot (4 f4 per row)
#pragma unroll
    for (int i = 0; i < BMt * BKt / 1024; ++i) {
      int idx = tid + i * 256;
      int row = idx >> 2;
      int kq = (idx & 3) * 4;
      float4 av = make_float4(0.f, 0.f, 0.f, 0.f);
      if (bm + row < M)
        av = *reinterpret_cast<const float4*>(A + (size_t)(bm + row) * lda + k0 + kq);
      As[kq + 0][row] = av.x; As[kq + 1][row] = av.y;
      As[kq + 2][row] = av.z; As[kq + 3][row] = av.w;
    }
    {
      int bk = tid >> 4, bn4 = (tid & 15) * 4;
      *reinterpret_cast<float4*>(&Bs[bk][bn4]) =
          *reinterpret_cast<const float4*>(B + (size_t)(k0 + bk) * ldb + bn + bn4);
    }
    __syncthreads();
#pragma unroll
    for (int k = 0; k < BKt; ++k) {
      float a[TM], b[4];
#pragma unroll
      for (int i = 0; i < TM; ++i) a[i] = As[k][tm + i];
#pragma unroll
      for (int j = 0; j < 4; ++j) b[j] = Bs[k][tn + j];
#pragma unroll
      for (int i = 0; i < TM; ++i)
#pragma unroll
        for (int j = 0; j < 4; ++j) acc[i][j] = fmaf(a[i], b[j], acc[i][j]);
    }
    __syncthreads();
  }
  float4 bz = make_float4(0.f, 0.f, 0.f, 0.f);
  if (bias) bz = *reinterpret_cast<const float4*>(bias + (size_t)z * biasZ + bn + tn);
#pragma unroll
  for (int i = 0; i < TM; ++i) {
    int m = bm + tm + i;
    if (m < M) {
      float4 o;
      o.x = acc[i][0] + bz.x; o.y = acc[i][1] + bz.y;
      o.z = acc[i][2] + bz.z; o.w = acc[i][3] + bz.w;
      *reinterpret_cast<float4*>(C + (size_t)m * ldc + bn + tn) = o;
    }
  }
}

// ==================== attention weight-vector prep ====================
// watt[f][c] = sum_j W[f, k*64+j] * att[k][j], c<8: att_src (k=c), c>=8: att_dst

__global__ void prep_watt_kernel(const float* __restrict__ W, const float* __restrict__ att_s,
                                 const float* __restrict__ att_d, float* __restrict__ watt,
                                 int F) {
  int idx = blockIdx.x * 256 + threadIdx.x;
  if (idx >= F * 16) return;
  int f = idx >> 4, c = idx & 15;
  int k = c & 7;
  const float* att = ((c < 8) ? att_s : att_d) + k * 64;
  const float* w = W + (size_t)f * 512 + k * 64;
  float s = 0.f;
#pragma unroll
  for (int j = 0; j < 64; ++j) s = fmaf(w[j], att[j], s);
  watt[idx] = s;
}

// ==================== attention coefficients ====================
// a_{s,d}[n,k] = sum_f feat[n,f] * watt[f][c]. 16 nodes per block, LDS-staged.

template <int F>
__global__ __launch_bounds__(256) void attcoef_kernel(
    const float* __restrict__ feat, const float* __restrict__ watt,
    float* __restrict__ a_s, float* __restrict__ a_d, int n) {
  __shared__ float rows[16 * F];
  __shared__ float wbuf[F * 16];
  const int n0 = blockIdx.x * 16;
  const int tid = threadIdx.x;
  if (n0 + 16 <= n) {
    const float4* g = reinterpret_cast<const float4*>(feat + (size_t)n0 * F);
    float4* l = reinterpret_cast<float4*>(rows);
    for (int i = tid; i < 16 * F / 4; i += 256) l[i] = g[i];
  } else {
    for (int i = tid; i < 16 * F; i += 256) {
      int r = i / F;
      rows[i] = (n0 + r < n) ? feat[(size_t)(n0 + r) * F + (i - r * F)] : 0.f;
    }
  }
  {
    const float4* g = reinterpret_cast<const float4*>(watt);
    float4* l = reinterpret_cast<float4*>(wbuf);
    for (int i = tid; i < F * 16 / 4; i += 256) l[i] = g[i];
  }
  __syncthreads();
  const int local = tid >> 4, c = tid & 15;
  float s = 0.f;
#pragma unroll 8
  for (int f = 0; f < F; ++f) s = fmaf(rows[local * F + f], wbuf[f * 16 + c], s);
  const int node = n0 + local;
  if (node < n) {
    if (c < 8) a_s[(size_t)node * 8 + c] = s;
    else       a_d[(size_t)node * 8 + (c - 8)] = s;
  }
}

// ==================== GAT pre-aggregation: one WAVE per dst node ====================
// 4 independent waves per block, no __syncthreads. Per-head softmax denom via
// shuffle reductions (no max subtraction: |a_s+a_d| < ~8, exp safe). Alpha for
// chunks of 8 edges staged in per-wave LDS (DS ops are in-order within a wave);
// feature pass gathers float4 rows with EPI edges in flight per iteration.

template <int F>
__global__ __launch_bounds__(256) void gat_aggregate_wave(
    const float* __restrict__ feat, const float* __restrict__ a_s,
    const float* __restrict__ a_d, const int* __restrict__ rowptr,
    const int* __restrict__ col, float* __restrict__ agg, int n) {
  constexpr int F4 = F / 4;    // float4s per row: 32 (F=128) or 16 (F=64)
  constexpr int EPI = 64 / F4; // edges in flight: 2 or 4
  constexpr int HPL = 8 / EPI; // heads stored per lane: 4 or 2
  __shared__ float s_alpha[4][8][8];  // [wave][edge-slot][head]
  const int wid = threadIdx.x >> 6;
  const int lane = threadIdx.x & 63;
  const int node = blockIdx.x * 4 + wid;
  if (node >= n) return;
  const int start = rowptr[node];
  const int deg = rowptr[node + 1] - start;
  const int j = lane >> 3;  // edge slot (alpha role)
  const int h = lane & 7;   // head (alpha role)
  const float adh = a_d[(size_t)node * 8 + h];
  // denom pass: den_h = sum_e exp(leaky(a_s[src,h] + a_d[node,h]))
  float den = 0.f;
  for (int e = j; e < deg; e += 8) {
    int s = col[start + e];
    float v = a_s[(size_t)s * 8 + h] + adh;
    v = (v > 0.f) ? v : 0.2f * v;
    den += __expf(v);
  }
  den += __shfl_xor(den, 8);
  den += __shfl_xor(den, 16);
  den += __shfl_xor(den, 32);
  const float inv = 1.f / (den + 1e-16f);
  // feature pass
  const int f4 = lane & (F4 - 1);
  const int ep = lane / F4;
  float4 acc[8];
#pragma unroll
  for (int k = 0; k < 8; ++k) acc[k] = make_float4(0.f, 0.f, 0.f, 0.f);
  for (int c0 = 0; c0 < deg; c0 += 8) {
    float aval = 0.f;
    if (c0 + j < deg) {
      int s = col[start + c0 + j];
      float v = a_s[(size_t)s * 8 + h] + adh;
      v = (v > 0.f) ? v : 0.2f * v;
      aval = __expf(v) * inv;
    }
    s_alpha[wid][j][h] = aval;
    __builtin_amdgcn_wave_barrier();
    const int ce = min(8, deg - c0);
    const float* s_al = &s_alpha[wid][0][0];
    for (int q = ep; q < ce; q += EPI) {
      int s = col[start + c0 + q];
      float4 fv = *reinterpret_cast<const float4*>(feat + (size_t)s * F + f4 * 4);
      float4 al = *reinterpret_cast<const float4*>(s_al + q * 8);
      float4 ah = *reinterpret_cast<const float4*>(s_al + q * 8 + 4);
      float av8[8] = {al.x, al.y, al.z, al.w, ah.x, ah.y, ah.z, ah.w};
#pragma unroll
      for (int hh = 0; hh < 8; ++hh) {
        acc[hh].x = fmaf(av8[hh], fv.x, acc[hh].x);
        acc[hh].y = fmaf(av8[hh], fv.y, acc[hh].y);
        acc[hh].z = fmaf(av8[hh], fv.z, acc[hh].z);
        acc[hh].w = fmaf(av8[hh], fv.w, acc[hh].w);
      }
    }
    __builtin_amdgcn_wave_barrier();
  }
  // reduce across edge sub-slots (lanes differing in ep bits)
#pragma unroll
  for (int hh = 0; hh < 8; ++hh) {
    for (int d = F4; d < 64; d <<= 1) {
      acc[hh].x += __shfl_xor(acc[hh].x, d);
      acc[hh].y += __shfl_xor(acc[hh].y, d);
      acc[hh].z += __shfl_xor(acc[hh].z, d);
      acc[hh].w += __shfl_xor(acc[hh].w, d);
    }
  }
  // store: lane writes HPL heads for its f4 slice
#pragma unroll
  for (int k = 0; k < HPL; ++k) {
    int hh = (lane / F4) * HPL + k;
    *reinterpret_cast<float4*>(agg + (size_t)node * 8 * F + (size_t)hh * F + f4 * 4) = acc[hh];
  }
}

// ==================== LSTM prep + activation ====================
// Only i,g,o gates needed (f gate multiplies c0=0). Packed 192 columns.

__global__ void prep_lstm_kernel(const float* __restrict__ W_ih, const float* __restrict__ b_ih,
                                 const float* __restrict__ b_hh, float* __restrict__ Wt,
                                 float* __restrict__ bsum) {
  int idx = blockIdx.x * 256 + threadIdx.x;
  if (idx < 512 * 192) {
    int k = idx / 192, jp = idx - k * 192;
    int j = (jp < 64) ? jp : jp + 64;
    Wt[idx] = W_ih[(size_t)j * 512 + k];
  }
  if (idx < 192) {
    int j = (idx < 64) ? idx : idx + 64;
    bsum[idx] = b_ih[j] + b_hh[j];
  }
}

__global__ void lstm_act_kernel(const float* __restrict__ gates, float* __restrict__ h2, int n) {
  int idx = blockIdx.x * 256 + threadIdx.x;
  if (idx >= n * 64) return;
  int node = idx >> 6, j = idx & 63;
  const float* g = gates + (size_t)node * 192;
  float iv = g[j], gv = g[64 + j], ov = g[128 + j];
  float c = (1.f / (1.f + expf(-iv))) * tanhf(gv);
  float hh = (1.f / (1.f + expf(-ov))) * tanhf(c);
  h2[idx] = fmaxf(hh, 0.f);  // fused relu
}

// ==================== final row softmax (512 wide) ====================

__global__ __launch_bounds__(256) void softmax512_kernel(const float* __restrict__ in,
                                                         float* __restrict__ out) {
  const int node = blockIdx.x;
  const int tid = threadIdx.x;
  __shared__ float red[256];
  float v0 = in[(size_t)node * 512 + tid];
  float v1 = in[(size_t)node * 512 + 256 + tid];
  red[tid] = fmaxf(v0, v1);
  __syncthreads();
  for (int s = 128; s >= 1; s >>= 1) {
    if (tid < s) red[tid] = fmaxf(red[tid], red[tid + s]);
    __syncthreads();
  }
  float mm = red[0];
  __syncthreads();
  float e0 = expf(v0 - mm), e1 = expf(v1 - mm);
  red[tid] = e0 + e1;
  __syncthreads();
  for (int s = 128; s >= 1; s >>= 1) {
    if (tid < s) red[tid] += red[tid + s];
    __syncthreads();
  }
  float inv = 1.f / red[0];
  out[(size_t)node * 512 + tid] = e0 * inv;
  out[(size_t)node * 512 + 256 + tid] = e1 * inv;
}

// ============================ launch ============================

extern "C" void kernel_launch(void* const* d_in, const int* in_sizes, int n_in,
                              void* d_out, int out_size, void* d_ws, size_t ws_size,
                              hipStream_t stream) {
  const float* x      = (const float*)d_in[0];
  const int*   ei     = (const int*)d_in[1];
  const float* W1     = (const float*)d_in[3];
  const float* att_s1 = (const float*)d_in[4];
  const float* att_d1 = (const float*)d_in[5];
  const float* bias1  = (const float*)d_in[6];
  const float* W_ih   = (const float*)d_in[7];
  const float* b_ih   = (const float*)d_in[9];
  const float* b_hh   = (const float*)d_in[10];
  const float* W2     = (const float*)d_in[11];
  const float* att_s2 = (const float*)d_in[12];
  const float* att_d2 = (const float*)d_in[13];
  const float* bias2  = (const float*)d_in[14];
  float* out = (float*)d_out;

  const int N = in_sizes[0] / 128;
  const int E = in_sizes[1] / 2;
  const int* src = ei;
  const int* dst = ei + E;

  char* p = (char*)d_ws;
  auto alloc = [&](size_t bytes) {
    char* r = p;
    p += (bytes + 255) & ~(size_t)255;
    return r;
  };
  float* slotA = (float*)alloc((size_t)N * 1024 * 4);  // agg1; later gates+h2+agg2
  float* slotB = (float*)alloc((size_t)N * 512 * 4);   // g1; later h3p
  float* a_s1 = (float*)alloc((size_t)N * 8 * 4);
  float* a_d1 = (float*)alloc((size_t)N * 8 * 4);
  float* a_s2 = (float*)alloc((size_t)N * 8 * 4);
  float* a_d2 = (float*)alloc((size_t)N * 8 * 4);
  float* watt1 = (float*)alloc(128 * 16 * 4);
  float* watt2 = (float*)alloc(64 * 16 * 4);
  float* Wt   = (float*)alloc((size_t)512 * 192 * 4);
  float* bsum = (float*)alloc(192 * 4);
  int* deg    = (int*)alloc((size_t)2 * N * 4);  // deg + wp adjacent (one memset)
  int* wp     = deg + N;
  int* rowptr = (int*)alloc((size_t)(N + 1) * 4);
  int* col    = (int*)alloc((size_t)(E + N) * 4);

  float* agg1  = slotA;                    // [N,8,128]
  float* g1    = slotB;                    // [N,512]
  float* gates = slotA;                    // [N,192]
  float* h2    = slotA + (size_t)N * 192;  // [N,64]
  float* agg2  = slotA + (size_t)N * 320;  // [N,8,64]
  float* h3p   = slotB;                    // [N,512] logits

  // ---- CSR build ----
  hipMemsetAsync(deg, 0, (size_t)2 * N * 4, stream);
  count_kernel<<<(E + 255) / 256, 256, 0, stream>>>(dst, deg, E);
  scan_kernel<<<1, 1024, 0, stream>>>(deg, rowptr, N);
  scatter_kernel<<<(E + N + 255) / 256, 256, 0, stream>>>(src, dst, rowptr, wp, col, E, N);

  // ---- weight prep ----
  prep_watt_kernel<<<(128 * 16 + 255) / 256, 256, 0, stream>>>(W1, att_s1, att_d1, watt1, 128);
  prep_watt_kernel<<<(64 * 16 + 255) / 256, 256, 0, stream>>>(W2, att_s2, att_d2, watt2, 64);
  prep_lstm_kernel<<<(512 * 192 + 255) / 256, 256, 0, stream>>>(W_ih, b_ih, b_hh, Wt, bsum);

  // ---- GATConv1: coeffs on x, aggregate x, project ----
  attcoef_kernel<128><<<(N + 15) / 16, 256, 0, stream>>>(x, watt1, a_s1, a_d1, N);
  gat_aggregate_wave<128><<<(N + 3) / 4, 256, 0, stream>>>(x, a_s1, a_d1, rowptr, col, agg1, N);
  {
    dim3 g(1, (N + 127) / 128, 8);
    gemm_kernel<128><<<g, 256, 0, stream>>>(agg1, W1, g1, bias1,
                                            N, 128, 1024, 512, 512, 128, 64, 64, 64);
  }

  // ---- LSTM (single step, h0=c0=0) ----
  {
    dim3 g(3, (N + 63) / 64, 1);
    gemm_kernel<64><<<g, 256, 0, stream>>>(g1, Wt, gates, bsum,
                                           N, 512, 512, 192, 192, 0, 0, 0, 0);
  }
  lstm_act_kernel<<<(N * 64 + 255) / 256, 256, 0, stream>>>(gates, h2, N);

  // ---- GATConv2: coeffs on h2, aggregate h2, project, row softmax ----
  attcoef_kernel<64><<<(N + 15) / 16, 256, 0, stream>>>(h2, watt2, a_s2, a_d2, N);
  gat_aggregate_wave<64><<<(N + 3) / 4, 256, 0, stream>>>(h2, a_s2, a_d2, rowptr, col, agg2, N);
  {
    dim3 g(1, (N + 127) / 128, 8);
    gemm_kernel<128><<<g, 256, 0, stream>>>(agg2, W2, h3p, bias2,
                                            N, 64, 512, 512, 512, 64, 64, 64, 64);
  }
  softmax512_kernel<<<N, 256, 0, stream>>>(h3p, out);
}

// Round 4
// 403.708 us; speedup vs baseline: 1.3225x; 1.3225x over previous
//
#include <hip/hip_runtime.h>
#include <math.h>

// ============================ CSR build ============================

__global__ void count_kernel(const int* __restrict__ dst, int* __restrict__ deg, int E) {
  int i = blockIdx.x * 256 + threadIdx.x;
  if (i < E) atomicAdd(&deg[dst[i]], 1);
}

// exclusive scan of (deg[i]+1) (+1 = self loop); single block, 8 vals/thread
__global__ void scan_kernel(const int* __restrict__ deg, int* __restrict__ rowptr, int n) {
  __shared__ int buf[1024];
  __shared__ int carry;
  if (threadIdx.x == 0) carry = 0;
  __syncthreads();
  for (int base = 0; base < n; base += 8192) {
    int v[8];
    int tsum = 0;
    int i0 = base + (int)threadIdx.x * 8;
#pragma unroll
    for (int k = 0; k < 8; ++k) {
      int i = i0 + k;
      v[k] = (i < n) ? (deg[i] + 1) : 0;
      tsum += v[k];
    }
    int incl = tsum;
    buf[threadIdx.x] = incl;
    __syncthreads();
    for (int s = 1; s < 1024; s <<= 1) {
      int t = (threadIdx.x >= (unsigned)s) ? buf[threadIdx.x - s] : 0;
      __syncthreads();
      incl += t;
      buf[threadIdx.x] = incl;
      __syncthreads();
    }
    int excl = carry + incl - tsum;
#pragma unroll
    for (int k = 0; k < 8; ++k) {
      int i = i0 + k;
      if (i < n) rowptr[i] = excl;
      excl += v[k];
    }
    int total = buf[1023];
    __syncthreads();
    if (threadIdx.x == 0) carry += total;
    __syncthreads();
  }
  if (threadIdx.x == 0) rowptr[n] = carry;
}

__global__ void scatter_kernel(const int* __restrict__ src, const int* __restrict__ dst,
                               const int* __restrict__ rowptr, int* __restrict__ wp,
                               int* __restrict__ col, int E, int n) {
  int i = blockIdx.x * 256 + threadIdx.x;
  if (i < E) {
    int d = dst[i];
    int p = rowptr[d] + atomicAdd(&wp[d], 1);
    col[p] = src[i];
  } else if (i < E + n) {
    int d = i - E;
    int p = rowptr[d] + atomicAdd(&wp[d], 1);
    col[p] = d;
  }
}

// ============================ fp32 GEMM ============================
// C[M,*] = A[M,K] @ B[K,*] (+bias). blockIdx.z adds aZ/bZ/cZ/biasZ element
// offsets (per-head batched projections). BN=64, BK=16, 256 threads,
// per-thread (BMt/16)x4 accumulator.

template <int BMt>
__global__ __launch_bounds__(256) void gemm_kernel(
    const float* __restrict__ A, const float* __restrict__ B,
    float* __restrict__ C, const float* __restrict__ bias,
    int M, int K, int lda, int ldb, int ldc,
    int aZ, int bZ, int cZ, int biasZ) {
  constexpr int BNt = 64, BKt = 16;
  constexpr int TM = BMt / 16;  // rows per thread (8 or 4)
  __shared__ float As[BKt][BMt + 4];
  __shared__ float Bs[BKt][BNt];
  const int z = blockIdx.z;
  A += (size_t)z * aZ;
  B += (size_t)z * bZ;
  C += (size_t)z * cZ;
  const int tid = threadIdx.x;
  const int bm = blockIdx.y * BMt;
  const int bn = blockIdx.x * BNt;
  const int tm = (tid >> 4) * TM;
  const int tn = (tid & 15) * 4;
  float acc[TM][4] = {};
  for (int k0 = 0; k0 < K; k0 += BKt) {
#pragma unroll
    for (int i = 0; i < BMt * BKt / 1024; ++i) {
      int idx = tid + i * 256;
      int row = idx >> 2;
      int kq = (idx & 3) * 4;
      float4 av = make_float4(0.f, 0.f, 0.f, 0.f);
      if (bm + row < M)
        av = *reinterpret_cast<const float4*>(A + (size_t)(bm + row) * lda + k0 + kq);
      As[kq + 0][row] = av.x; As[kq + 1][row] = av.y;
      As[kq + 2][row] = av.z; As[kq + 3][row] = av.w;
    }
    {
      int bk = tid >> 4, bn4 = (tid & 15) * 4;
      *reinterpret_cast<float4*>(&Bs[bk][bn4]) =
          *reinterpret_cast<const float4*>(B + (size_t)(k0 + bk) * ldb + bn + bn4);
    }
    __syncthreads();
#pragma unroll
    for (int k = 0; k < BKt; ++k) {
      float a[TM], b[4];
#pragma unroll
      for (int i = 0; i < TM; ++i) a[i] = As[k][tm + i];
#pragma unroll
      for (int j = 0; j < 4; ++j) b[j] = Bs[k][tn + j];
#pragma unroll
      for (int i = 0; i < TM; ++i)
#pragma unroll
        for (int j = 0; j < 4; ++j) acc[i][j] = fmaf(a[i], b[j], acc[i][j]);
    }
    __syncthreads();
  }
  float4 bz = make_float4(0.f, 0.f, 0.f, 0.f);
  if (bias) bz = *reinterpret_cast<const float4*>(bias + (size_t)z * biasZ + bn + tn);
#pragma unroll
  for (int i = 0; i < TM; ++i) {
    int m = bm + tm + i;
    if (m < M) {
      float4 o;
      o.x = acc[i][0] + bz.x; o.y = acc[i][1] + bz.y;
      o.z = acc[i][2] + bz.z; o.w = acc[i][3] + bz.w;
      *reinterpret_cast<float4*>(C + (size_t)m * ldc + bn + tn) = o;
    }
  }
}

// ==================== attention weight-vector prep ====================
// watt[f][c] = sum_j W[f, k*64+j] * att[k][j], c<8: att_src (k=c), c>=8: att_dst

__global__ void prep_watt_kernel(const float* __restrict__ W, const float* __restrict__ att_s,
                                 const float* __restrict__ att_d, float* __restrict__ watt,
                                 int F) {
  int idx = blockIdx.x * 256 + threadIdx.x;
  if (idx >= F * 16) return;
  int f = idx >> 4, c = idx & 15;
  int k = c & 7;
  const float* att = ((c < 8) ? att_s : att_d) + k * 64;
  const float* w = W + (size_t)f * 512 + k * 64;
  float s = 0.f;
#pragma unroll
  for (int j = 0; j < 64; ++j) s = fmaf(w[j], att[j], s);
  watt[idx] = s;
}

// ==================== attention coefficients ====================
// a_{s,d}[n,k] = sum_f feat[n,f] * watt[f][c]. 16 nodes per block, LDS-staged.

template <int F>
__global__ __launch_bounds__(256) void attcoef_kernel(
    const float* __restrict__ feat, const float* __restrict__ watt,
    float* __restrict__ a_s, float* __restrict__ a_d, int n) {
  __shared__ float rows[16 * F];
  __shared__ float wbuf[F * 16];
  const int n0 = blockIdx.x * 16;
  const int tid = threadIdx.x;
  if (n0 + 16 <= n) {
    const float4* g = reinterpret_cast<const float4*>(feat + (size_t)n0 * F);
    float4* l = reinterpret_cast<float4*>(rows);
    for (int i = tid; i < 16 * F / 4; i += 256) l[i] = g[i];
  } else {
    for (int i = tid; i < 16 * F; i += 256) {
      int r = i / F;
      rows[i] = (n0 + r < n) ? feat[(size_t)(n0 + r) * F + (i - r * F)] : 0.f;
    }
  }
  {
    const float4* g = reinterpret_cast<const float4*>(watt);
    float4* l = reinterpret_cast<float4*>(wbuf);
    for (int i = tid; i < F * 16 / 4; i += 256) l[i] = g[i];
  }
  __syncthreads();
  const int local = tid >> 4, c = tid & 15;
  float s = 0.f;
#pragma unroll 8
  for (int f = 0; f < F; ++f) s = fmaf(rows[local * F + f], wbuf[f * 16 + c], s);
  const int node = n0 + local;
  if (node < n) {
    if (c < 8) a_s[(size_t)node * 8 + c] = s;
    else       a_d[(size_t)node * 8 + (c - 8)] = s;
  }
}

// ==================== GAT pre-aggregation: one WAVE per dst node ====================
// 4 independent waves/block, no __syncthreads. Heads are split across lane
// GROUPS (F=128: 2 groups x 4 heads; F=64: 4 groups x 2 heads); every group
// walks all edges, so accumulators are explicit float4 scalars (no indexed
// local arrays -> no scratch spill, the R3 failure). Alpha + col staged in
// per-wave LDS chunks of 8 edges; DS ops are wave-ordered (wave_barrier pins
// the compiler schedule). No max-subtraction: |a_s+a_d| <~ 8 so exp is safe.

template <int F>
__global__ __launch_bounds__(256) void gat_aggregate_wave(
    const float* __restrict__ feat, const float* __restrict__ a_s,
    const float* __restrict__ a_d, const int* __restrict__ rowptr,
    const int* __restrict__ col, float* __restrict__ agg, int n) {
  constexpr int F4 = F / 4;              // float4 slots per row: 32 or 16
  constexpr int HPG = (F == 128) ? 4 : 2;  // heads per lane-group
  __shared__ float s_alpha[4][8][8];  // [wave][edge-slot][head]
  __shared__ int s_cols[4][8];
  const int wid = threadIdx.x >> 6;
  const int lane = threadIdx.x & 63;
  const int node = blockIdx.x * 4 + wid;
  if (node >= n) return;
  const int start = rowptr[node];
  const int deg = rowptr[node + 1] - start;
  const int j = lane >> 3;  // edge slot (alpha role)
  const int h = lane & 7;   // head (alpha role)
  const float adh = a_d[(size_t)node * 8 + h];
  // denom pass: den_h = sum_e exp(leaky(a_s[src,h] + a_d[node,h]))
  float den = 0.f;
  for (int e = j; e < deg; e += 8) {
    int s = col[start + e];
    float v = a_s[(size_t)s * 8 + h] + adh;
    v = (v > 0.f) ? v : 0.2f * v;
    den += __expf(v);
  }
  den += __shfl_xor(den, 8);
  den += __shfl_xor(den, 16);
  den += __shfl_xor(den, 32);
  const float inv = 1.f / (den + 1e-16f);
  // feature pass: lane owns float4 slice f4 of heads [hbase, hbase+HPG)
  const int f4 = lane & (F4 - 1);
  const int hbase = (lane / F4) * HPG;
  float4 acc0 = make_float4(0.f, 0.f, 0.f, 0.f);
  float4 acc1 = make_float4(0.f, 0.f, 0.f, 0.f);
  float4 acc2 = make_float4(0.f, 0.f, 0.f, 0.f);
  float4 acc3 = make_float4(0.f, 0.f, 0.f, 0.f);
  for (int c0 = 0; c0 < deg; c0 += 8) {
    float aval = 0.f;
    int sj = 0;
    if (c0 + j < deg) {
      sj = col[start + c0 + j];
      float v = a_s[(size_t)sj * 8 + h] + adh;
      v = (v > 0.f) ? v : 0.2f * v;
      aval = __expf(v) * inv;
    }
    s_alpha[wid][j][h] = aval;
    if (h == 0) s_cols[wid][j] = sj;
    __builtin_amdgcn_wave_barrier();
    const int ce = min(8, deg - c0);
    for (int e = 0; e < ce; ++e) {
      int s = s_cols[wid][e];
      float4 fv = *reinterpret_cast<const float4*>(feat + (size_t)s * F + f4 * 4);
      if constexpr (HPG == 4) {
        float4 al = *reinterpret_cast<const float4*>(&s_alpha[wid][e][hbase]);
        acc0.x = fmaf(al.x, fv.x, acc0.x); acc0.y = fmaf(al.x, fv.y, acc0.y);
        acc0.z = fmaf(al.x, fv.z, acc0.z); acc0.w = fmaf(al.x, fv.w, acc0.w);
        acc1.x = fmaf(al.y, fv.x, acc1.x); acc1.y = fmaf(al.y, fv.y, acc1.y);
        acc1.z = fmaf(al.y, fv.z, acc1.z); acc1.w = fmaf(al.y, fv.w, acc1.w);
        acc2.x = fmaf(al.z, fv.x, acc2.x); acc2.y = fmaf(al.z, fv.y, acc2.y);
        acc2.z = fmaf(al.z, fv.z, acc2.z); acc2.w = fmaf(al.z, fv.w, acc2.w);
        acc3.x = fmaf(al.w, fv.x, acc3.x); acc3.y = fmaf(al.w, fv.y, acc3.y);
        acc3.z = fmaf(al.w, fv.z, acc3.z); acc3.w = fmaf(al.w, fv.w, acc3.w);
      } else {
        float2 al = *reinterpret_cast<const float2*>(&s_alpha[wid][e][hbase]);
        acc0.x = fmaf(al.x, fv.x, acc0.x); acc0.y = fmaf(al.x, fv.y, acc0.y);
        acc0.z = fmaf(al.x, fv.z, acc0.z); acc0.w = fmaf(al.x, fv.w, acc0.w);
        acc1.x = fmaf(al.y, fv.x, acc1.x); acc1.y = fmaf(al.y, fv.y, acc1.y);
        acc1.z = fmaf(al.y, fv.z, acc1.z); acc1.w = fmaf(al.y, fv.w, acc1.w);
      }
    }
    __builtin_amdgcn_wave_barrier();
  }
  float* outp = agg + (size_t)node * 8 * F + (size_t)hbase * F + f4 * 4;
  *reinterpret_cast<float4*>(outp) = acc0;
  *reinterpret_cast<float4*>(outp + F) = acc1;
  if constexpr (HPG == 4) {
    *reinterpret_cast<float4*>(outp + 2 * F) = acc2;
    *reinterpret_cast<float4*>(outp + 3 * F) = acc3;
  }
}

// ==================== LSTM prep + activation ====================
// Only i,g,o gates needed (f gate multiplies c0=0). Packed 192 columns.

__global__ void prep_lstm_kernel(const float* __restrict__ W_ih, const float* __restrict__ b_ih,
                                 const float* __restrict__ b_hh, float* __restrict__ Wt,
                                 float* __restrict__ bsum) {
  int idx = blockIdx.x * 256 + threadIdx.x;
  if (idx < 512 * 192) {
    int k = idx / 192, jp = idx - k * 192;
    int j = (jp < 64) ? jp : jp + 64;
    Wt[idx] = W_ih[(size_t)j * 512 + k];
  }
  if (idx < 192) {
    int j = (idx < 64) ? idx : idx + 64;
    bsum[idx] = b_ih[j] + b_hh[j];
  }
}

__global__ void lstm_act_kernel(const float* __restrict__ gates, float* __restrict__ h2, int n) {
  int idx = blockIdx.x * 256 + threadIdx.x;
  if (idx >= n * 64) return;
  int node = idx >> 6, j = idx & 63;
  const float* g = gates + (size_t)node * 192;
  float iv = g[j], gv = g[64 + j], ov = g[128 + j];
  float c = (1.f / (1.f + expf(-iv))) * tanhf(gv);
  float hh = (1.f / (1.f + expf(-ov))) * tanhf(c);
  h2[idx] = fmaxf(hh, 0.f);  // fused relu
}

// ==================== final row softmax (512 wide) ====================

__global__ __launch_bounds__(256) void softmax512_kernel(const float* __restrict__ in,
                                                         float* __restrict__ out) {
  const int node = blockIdx.x;
  const int tid = threadIdx.x;
  __shared__ float red[256];
  float v0 = in[(size_t)node * 512 + tid];
  float v1 = in[(size_t)node * 512 + 256 + tid];
  red[tid] = fmaxf(v0, v1);
  __syncthreads();
  for (int s = 128; s >= 1; s >>= 1) {
    if (tid < s) red[tid] = fmaxf(red[tid], red[tid + s]);
    __syncthreads();
  }
  float mm = red[0];
  __syncthreads();
  float e0 = expf(v0 - mm), e1 = expf(v1 - mm);
  red[tid] = e0 + e1;
  __syncthreads();
  for (int s = 128; s >= 1; s >>= 1) {
    if (tid < s) red[tid] += red[tid + s];
    __syncthreads();
  }
  float inv = 1.f / red[0];
  out[(size_t)node * 512 + tid] = e0 * inv;
  out[(size_t)node * 512 + 256 + tid] = e1 * inv;
}

// ============================ launch ============================

extern "C" void kernel_launch(void* const* d_in, const int* in_sizes, int n_in,
                              void* d_out, int out_size, void* d_ws, size_t ws_size,
                              hipStream_t stream) {
  const float* x      = (const float*)d_in[0];
  const int*   ei     = (const int*)d_in[1];
  const float* W1     = (const float*)d_in[3];
  const float* att_s1 = (const float*)d_in[4];
  const float* att_d1 = (const float*)d_in[5];
  const float* bias1  = (const float*)d_in[6];
  const float* W_ih   = (const float*)d_in[7];
  const float* b_ih   = (const float*)d_in[9];
  const float* b_hh   = (const float*)d_in[10];
  const float* W2     = (const float*)d_in[11];
  const float* att_s2 = (const float*)d_in[12];
  const float* att_d2 = (const float*)d_in[13];
  const float* bias2  = (const float*)d_in[14];
  float* out = (float*)d_out;

  const int N = in_sizes[0] / 128;
  const int E = in_sizes[1] / 2;
  const int* src = ei;
  const int* dst = ei + E;

  char* p = (char*)d_ws;
  auto alloc = [&](size_t bytes) {
    char* r = p;
    p += (bytes + 255) & ~(size_t)255;
    return r;
  };
  float* slotA = (float*)alloc((size_t)N * 1024 * 4);  // agg1; later gates+h2+agg2
  float* slotB = (float*)alloc((size_t)N * 512 * 4);   // g1; later h3p
  float* a_s1 = (float*)alloc((size_t)N * 8 * 4);
  float* a_d1 = (float*)alloc((size_t)N * 8 * 4);
  float* a_s2 = (float*)alloc((size_t)N * 8 * 4);
  float* a_d2 = (float*)alloc((size_t)N * 8 * 4);
  float* watt1 = (float*)alloc(128 * 16 * 4);
  float* watt2 = (float*)alloc(64 * 16 * 4);
  float* Wt   = (float*)alloc((size_t)512 * 192 * 4);
  float* bsum = (float*)alloc(192 * 4);
  int* deg    = (int*)alloc((size_t)2 * N * 4);  // deg + wp adjacent (one memset)
  int* wp     = deg + N;
  int* rowptr = (int*)alloc((size_t)(N + 1) * 4);
  int* col    = (int*)alloc((size_t)(E + N) * 4);

  float* agg1  = slotA;                    // [N,8,128]
  float* g1    = slotB;                    // [N,512]
  float* gates = slotA;                    // [N,192]
  float* h2    = slotA + (size_t)N * 192;  // [N,64]
  float* agg2  = slotA + (size_t)N * 320;  // [N,8,64]
  float* h3p   = slotB;                    // [N,512] logits

  // ---- CSR build ----
  hipMemsetAsync(deg, 0, (size_t)2 * N * 4, stream);
  count_kernel<<<(E + 255) / 256, 256, 0, stream>>>(dst, deg, E);
  scan_kernel<<<1, 1024, 0, stream>>>(deg, rowptr, N);
  scatter_kernel<<<(E + N + 255) / 256, 256, 0, stream>>>(src, dst, rowptr, wp, col, E, N);

  // ---- weight prep ----
  prep_watt_kernel<<<(128 * 16 + 255) / 256, 256, 0, stream>>>(W1, att_s1, att_d1, watt1, 128);
  prep_watt_kernel<<<(64 * 16 + 255) / 256, 256, 0, stream>>>(W2, att_s2, att_d2, watt2, 64);
  prep_lstm_kernel<<<(512 * 192 + 255) / 256, 256, 0, stream>>>(W_ih, b_ih, b_hh, Wt, bsum);

  // ---- GATConv1: coeffs on x, aggregate x, project ----
  attcoef_kernel<128><<<(N + 15) / 16, 256, 0, stream>>>(x, watt1, a_s1, a_d1, N);
  gat_aggregate_wave<128><<<(N + 3) / 4, 256, 0, stream>>>(x, a_s1, a_d1, rowptr, col, agg1, N);
  {
    dim3 g(1, (N + 127) / 128, 8);
    gemm_kernel<128><<<g, 256, 0, stream>>>(agg1, W1, g1, bias1,
                                            N, 128, 1024, 512, 512, 128, 64, 64, 64);
  }

  // ---- LSTM (single step, h0=c0=0) ----
  {
    dim3 g(3, (N + 63) / 64, 1);
    gemm_kernel<64><<<g, 256, 0, stream>>>(g1, Wt, gates, bsum,
                                           N, 512, 512, 192, 192, 0, 0, 0, 0);
  }
  lstm_act_kernel<<<(N * 64 + 255) / 256, 256, 0, stream>>>(gates, h2, N);

  // ---- GATConv2: coeffs on h2, aggregate h2, project, row softmax ----
  attcoef_kernel<64><<<(N + 15) / 16, 256, 0, stream>>>(h2, watt2, a_s2, a_d2, N);
  gat_aggregate_wave<64><<<(N + 3) / 4, 256, 0, stream>>>(h2, a_s2, a_d2, rowptr, col, agg2, N);
  {
    dim3 g(1, (N + 127) / 128, 8);
    gemm_kernel<128><<<g, 256, 0, stream>>>(agg2, W2, h3p, bias2,
                                            N, 64, 512, 512, 512, 64, 64, 64, 64);
  }
  softmax512_kernel<<<N, 256, 0, stream>>>(h3p, out);
}